// Round 2
// baseline (1150.982 us; speedup 1.0000x reference)
//
#include <hip/hip_runtime.h>

typedef __attribute__((ext_vector_type(8))) __bf16 bf16x8;
typedef __attribute__((ext_vector_type(4))) float f32x4;

__device__ __forceinline__ float bf2f(unsigned short u) {
    union { unsigned u; float f; } c; c.u = ((unsigned)u) << 16; return c.f;
}
__device__ __forceinline__ unsigned short f2bf(float f) {
    union { float f; unsigned u; } c; c.f = f;
    unsigned r = c.u + 0x7fffu + ((c.u >> 16) & 1u);  // RNE
    return (unsigned short)(r >> 16);
}

#define GLD_LDS16(g, l) \
    __builtin_amdgcn_global_load_lds( \
        (const __attribute__((address_space(1))) void*)(g), \
        (__attribute__((address_space(3))) void*)(l), 16, 0, 0)

// fp32 -> bf16 convert, up to 4 arrays selected by blockIdx.z, each 4096*4096.
__global__ void __launch_bounds__(256) cvt_f32_bf16(
    const float* __restrict__ s0, unsigned short* __restrict__ d0,
    const float* __restrict__ s1, unsigned short* __restrict__ d1,
    const float* __restrict__ s2, unsigned short* __restrict__ d2,
    const float* __restrict__ s3, unsigned short* __restrict__ d3)
{
    const float* s; unsigned short* d;
    if (blockIdx.z == 0)      { s = s0; d = d0; }
    else if (blockIdx.z == 1) { s = s1; d = d1; }
    else if (blockIdx.z == 2) { s = s2; d = d2; }
    else                      { s = s3; d = d3; }
    const size_t N = (size_t)4096 * 4096;
    const size_t stride = (size_t)gridDim.x * 256 * 4;
    for (size_t i = ((size_t)blockIdx.x * 256 + threadIdx.x) * 4; i < N; i += stride) {
        float4 v = *(const float4*)(s + i);
        ushort4 o;
        o.x = f2bf(v.x); o.y = f2bf(v.y); o.z = f2bf(v.z); o.w = f2bf(v.w);
        *(ushort4*)(d + i) = o;
    }
}

// C[m][n] = sum_k A[m][k] * W[n][k] + bias[n]; A,W bf16 4096x4096 row-major,
// bias fp32. OUTF32 selects fp32 vs bf16 C. grid=(32,32,z): z picks triple.
template <bool OUTF32>
__global__ void __launch_bounds__(256) gemm_bt(
    const unsigned short* __restrict__ A,
    const unsigned short* __restrict__ W0, const float* __restrict__ b0, void* __restrict__ C0,
    const unsigned short* __restrict__ W1, const float* __restrict__ b1, void* __restrict__ C1,
    const unsigned short* __restrict__ W2, const float* __restrict__ b2, void* __restrict__ C2)
{
    constexpr int K = 4096;
    const unsigned short* W; const float* bias; void* C;
    if (blockIdx.z == 0)      { W = W0; bias = b0; C = C0; }
    else if (blockIdx.z == 1) { W = W1; bias = b1; C = C1; }
    else                      { W = W2; bias = b2; C = C2; }

    __shared__ __align__(16) unsigned short sA[128 * 32];  // 8 KB
    __shared__ __align__(16) unsigned short sB[128 * 32];  // 8 KB

    const int tid  = threadIdx.x;
    const int lane = tid & 63;
    const int wave = tid >> 6;
    const int wm = wave >> 1;
    const int wn = wave & 1;
    const int m0 = blockIdx.y * 128;
    const int n0 = blockIdx.x * 128;

    // staging: one global_load_lds = 64 lanes x 16B = 16 rows x 32 cols
    const int srow = lane >> 2;
    const int scol = (lane & 3) << 3;
    const unsigned short* gA0 = A + (size_t)(m0 + wave * 16 + srow) * K + scol;
    const unsigned short* gA1 = gA0 + (size_t)64 * K;
    const unsigned short* gB0 = W + (size_t)(n0 + wave * 16 + srow) * K + scol;
    const unsigned short* gB1 = gB0 + (size_t)64 * K;
    unsigned short* lA0 = &sA[wave * 512];
    unsigned short* lA1 = &sA[(wave + 4) * 512];
    unsigned short* lB0 = &sB[wave * 512];
    unsigned short* lB1 = &sB[(wave + 4) * 512];

    f32x4 acc[4][4];
#pragma unroll
    for (int i = 0; i < 4; i++)
#pragma unroll
        for (int j = 0; j < 4; j++) acc[i][j] = (f32x4){0.f, 0.f, 0.f, 0.f};

    // A-fragment: lane holds A[m=lane&15][k=(lane>>4)*8+j]
    const int fl = lane & 15;
    const int fk = (lane >> 4) << 3;
    const unsigned short* aP0 = &sA[(wm * 64 + fl) * 32 + fk];
    const unsigned short* bP0 = &sB[(wn * 64 + fl) * 32 + fk];

    for (int k0 = 0; k0 < K; k0 += 32) {
        __syncthreads();
        GLD_LDS16(gA0 + k0, lA0);
        GLD_LDS16(gA1 + k0, lA1);
        GLD_LDS16(gB0 + k0, lB0);
        GLD_LDS16(gB1 + k0, lB1);
        __syncthreads();

        bf16x8 af[4], bfr[4];
#pragma unroll
        for (int i = 0; i < 4; i++) af[i]  = *(const bf16x8*)(aP0 + i * 512);
#pragma unroll
        for (int j = 0; j < 4; j++) bfr[j] = *(const bf16x8*)(bP0 + j * 512);
#pragma unroll
        for (int i = 0; i < 4; i++)
#pragma unroll
            for (int j = 0; j < 4; j++)
                acc[i][j] = __builtin_amdgcn_mfma_f32_16x16x32_bf16(af[i], bfr[j], acc[i][j], 0, 0, 0);
    }

    // C/D layout: col = lane&15, row = (lane>>4)*4 + r  [m89/m91-verified]
    const int r0 = (lane >> 4) << 2;
#pragma unroll
    for (int j = 0; j < 4; j++) {
        const int col = n0 + wn * 64 + j * 16 + fl;
        const float bj = bias[col];
#pragma unroll
        for (int i = 0; i < 4; i++) {
            const int row = m0 + wm * 64 + i * 16 + r0;
#pragma unroll
            for (int r = 0; r < 4; r++) {
                const float val = acc[i][j][r] + bj;
                if constexpr (OUTF32)
                    ((float*)C)[(size_t)(row + r) * 4096 + col] = val;
                else
                    ((unsigned short*)C)[(size_t)(row + r) * 4096 + col] = f2bf(val);
            }
        }
    }
}

// Per-token attention over the HEAD axis. One 64-thread block per (b,s) token.
// scores[h][e] = q[h]·k[e]/8 ; p = softmax_e ; vals[i][j] = sum_e p[i][e]*v[j][e]
// merged[(b*64+i)][(s*64+j)] = vals[i][j]
__global__ void __launch_bounds__(64) attn_kernel(
    const unsigned short* __restrict__ q, const unsigned short* __restrict__ k,
    const unsigned short* __restrict__ v, unsigned short* __restrict__ merged)
{
    __shared__ __align__(16) float kf[64 * 64];   // kf[e][d]
    __shared__ __align__(16) float vt[64 * 68];   // vt[e][j] = v[j][e], padded

    const int tid = threadIdx.x;
    const int token = blockIdx.x;
    const int b = token >> 6, s = token & 63;
    const size_t base = (size_t)token * 4096;

    const ushort4* kg4 = (const ushort4*)(k + base);
    const ushort4* vg4 = (const ushort4*)(v + base);
    for (int i = tid; i < 1024; i += 64) {
        ushort4 kk = kg4[i];
        ((float4*)kf)[i] = make_float4(bf2f(kk.x), bf2f(kk.y), bf2f(kk.z), bf2f(kk.w));
        ushort4 vv = vg4[i];
        const int h = i >> 4;
        const int d = (i & 15) << 2;
        vt[(d + 0) * 68 + h] = bf2f(vv.x);
        vt[(d + 1) * 68 + h] = bf2f(vv.y);
        vt[(d + 2) * 68 + h] = bf2f(vv.z);
        vt[(d + 3) * 68 + h] = bf2f(vv.w);
    }

    float qr[64];
    const ushort4* qg4 = (const ushort4*)(q + base + (size_t)tid * 64);
#pragma unroll
    for (int i = 0; i < 16; i++) {
        ushort4 qq = qg4[i];
        qr[4 * i + 0] = bf2f(qq.x); qr[4 * i + 1] = bf2f(qq.y);
        qr[4 * i + 2] = bf2f(qq.z); qr[4 * i + 3] = bf2f(qq.w);
    }
    __syncthreads();

    float m = -1e30f;
    for (int e = 0; e < 64; e++) {
        const float4* kr = (const float4*)(kf + e * 64);
        float acc = 0.f;
#pragma unroll
        for (int d4 = 0; d4 < 16; d4++) {
            float4 kv = kr[d4];
            acc += qr[4 * d4 + 0] * kv.x + qr[4 * d4 + 1] * kv.y
                 + qr[4 * d4 + 2] * kv.z + qr[4 * d4 + 3] * kv.w;
        }
        m = fmaxf(m, acc);
    }
    m *= 0.125f;

    float out[64];
#pragma unroll
    for (int j = 0; j < 64; j++) out[j] = 0.f;
    float l = 0.f;
    for (int e = 0; e < 64; e++) {
        const float4* kr = (const float4*)(kf + e * 64);
        float acc = 0.f;
#pragma unroll
        for (int d4 = 0; d4 < 16; d4++) {
            float4 kv = kr[d4];
            acc += qr[4 * d4 + 0] * kv.x + qr[4 * d4 + 1] * kv.y
                 + qr[4 * d4 + 2] * kv.z + qr[4 * d4 + 3] * kv.w;
        }
        const float p = __expf(acc * 0.125f - m);
        l += p;
        const float4* vr = (const float4*)(vt + e * 68);
#pragma unroll
        for (int j4 = 0; j4 < 16; j4++) {
            float4 vv = vr[j4];
            out[4 * j4 + 0] += p * vv.x; out[4 * j4 + 1] += p * vv.y;
            out[4 * j4 + 2] += p * vv.z; out[4 * j4 + 3] += p * vv.w;
        }
    }

    const float inv = 1.f / l;
    ushort4* outp = (ushort4*)(merged + (size_t)(b * 64 + tid) * 4096 + s * 64);
#pragma unroll
    for (int j4 = 0; j4 < 16; j4++) {
        ushort4 o;
        o.x = f2bf(out[4 * j4 + 0] * inv);
        o.y = f2bf(out[4 * j4 + 1] * inv);
        o.z = f2bf(out[4 * j4 + 2] * inv);
        o.w = f2bf(out[4 * j4 + 3] * inv);
        outp[j4] = o;
    }
}

extern "C" void kernel_launch(void* const* d_in, const int* in_sizes, int n_in,
                              void* d_out, int out_size, void* d_ws, size_t ws_size,
                              hipStream_t stream)
{
    // inputs are FP32 per the reference
    const float* x  = (const float*)d_in[0];
    const float* Wq = (const float*)d_in[1];
    const float* bq = (const float*)d_in[2];
    const float* Wk = (const float*)d_in[3];
    const float* bk = (const float*)d_in[4];
    const float* Wv = (const float*)d_in[5];
    const float* bv = (const float*)d_in[6];
    const float* Wp = (const float*)d_in[7];
    const float* bp = (const float*)d_in[8];
    float* out = (float*)d_out;

    const size_t MAT = (size_t)4096 * 4096;  // elements per bf16 slot (32 MB)
    unsigned short* s = (unsigned short*)d_ws;
    unsigned short* xb     = s + 0 * MAT;    // slot0: xb, later merged
    unsigned short* Wqb    = s + 1 * MAT;    // slot1: Wqb, later Wpb
    unsigned short* Wkb    = s + 2 * MAT;
    unsigned short* Wvb    = s + 3 * MAT;
    unsigned short* q      = s + 4 * MAT;
    unsigned short* k      = s + 5 * MAT;
    unsigned short* v      = s + 6 * MAT;    // total 7 slots = 235 MB
    unsigned short* merged = xb;             // x dead after QKV GEMM
    unsigned short* Wpb    = Wqb;            // Wq dead after QKV GEMM

    // 1. convert x, Wq, Wk, Wv to bf16
    cvt_f32_bf16<<<dim3(2048, 1, 4), 256, 0, stream>>>(x, xb, Wq, Wqb, Wk, Wkb, Wv, Wvb);
    // 2. QKV projections (fused)
    gemm_bt<false><<<dim3(32, 32, 3), 256, 0, stream>>>(
        xb, Wqb, bq, q, Wkb, bk, k, Wvb, bv, v);
    // 3. convert Wp into slot1 (Wq dead now)
    cvt_f32_bf16<<<dim3(2048, 1, 1), 256, 0, stream>>>(Wp, Wpb, Wp, Wpb, Wp, Wpb, Wp, Wpb);
    // 4. per-token head-axis attention -> merged (slot0)
    attn_kernel<<<dim3(4096), 64, 0, stream>>>(q, k, v, merged);
    // 5. output projection -> fp32 d_out
    gemm_bt<true><<<dim3(32, 32, 1), 256, 0, stream>>>(
        merged, Wpb, bp, out, Wpb, bp, out, Wpb, bp, out);
}

// Round 3
// 962.200 us; speedup vs baseline: 1.1962x; 1.1962x over previous
//
#include <hip/hip_runtime.h>

typedef __attribute__((ext_vector_type(8))) __bf16 bf16x8;
typedef __attribute__((ext_vector_type(4))) float f32x4;

__device__ __forceinline__ float bf2f(unsigned short u) {
    union { unsigned u; float f; } c; c.u = ((unsigned)u) << 16; return c.f;
}
__device__ __forceinline__ unsigned short f2bf(float f) {
    union { float f; unsigned u; } c; c.f = f;
    unsigned r = c.u + 0x7fffu + ((c.u >> 16) & 1u);  // RNE
    return (unsigned short)(r >> 16);
}

#define GLD_LDS16(g, l) \
    __builtin_amdgcn_global_load_lds( \
        (const __attribute__((address_space(1))) void*)(g), \
        (__attribute__((address_space(3))) void*)(l), 16, 0, 0)

// fp32 -> bf16 convert, up to 4 arrays selected by blockIdx.z, each 4096*4096.
__global__ void __launch_bounds__(256) cvt_f32_bf16(
    const float* __restrict__ s0, unsigned short* __restrict__ d0,
    const float* __restrict__ s1, unsigned short* __restrict__ d1,
    const float* __restrict__ s2, unsigned short* __restrict__ d2,
    const float* __restrict__ s3, unsigned short* __restrict__ d3)
{
    const float* s; unsigned short* d;
    if (blockIdx.z == 0)      { s = s0; d = d0; }
    else if (blockIdx.z == 1) { s = s1; d = d1; }
    else if (blockIdx.z == 2) { s = s2; d = d2; }
    else                      { s = s3; d = d3; }
    const size_t N = (size_t)4096 * 4096;
    const size_t stride = (size_t)gridDim.x * 256 * 4;
    for (size_t i = ((size_t)blockIdx.x * 256 + threadIdx.x) * 4; i < N; i += stride) {
        float4 v = *(const float4*)(s + i);
        ushort4 o;
        o.x = f2bf(v.x); o.y = f2bf(v.y); o.z = f2bf(v.z); o.w = f2bf(v.w);
        *(ushort4*)(d + i) = o;
    }
}

// C[m][n] = sum_k A[m][k] * W[n][k] + bias[n]; A,W bf16 4096x4096 row-major,
// bias fp32. OUTF32 selects fp32 vs bf16 C. grid=(32,32,z): z picks triple.
template <bool OUTF32>
__global__ void __launch_bounds__(256) gemm_bt(
    const unsigned short* __restrict__ A,
    const unsigned short* __restrict__ W0, const float* __restrict__ b0, void* __restrict__ C0,
    const unsigned short* __restrict__ W1, const float* __restrict__ b1, void* __restrict__ C1,
    const unsigned short* __restrict__ W2, const float* __restrict__ b2, void* __restrict__ C2)
{
    constexpr int K = 4096;
    const unsigned short* W; const float* bias; void* C;
    if (blockIdx.z == 0)      { W = W0; bias = b0; C = C0; }
    else if (blockIdx.z == 1) { W = W1; bias = b1; C = C1; }
    else                      { W = W2; bias = b2; C = C2; }

    __shared__ __align__(16) unsigned short sA[128 * 32];  // 8 KB
    __shared__ __align__(16) unsigned short sB[128 * 32];  // 8 KB

    const int tid  = threadIdx.x;
    const int lane = tid & 63;
    const int wave = tid >> 6;
    const int wm = wave >> 1;
    const int wn = wave & 1;
    const int m0 = blockIdx.y * 128;
    const int n0 = blockIdx.x * 128;

    // staging: one global_load_lds = 64 lanes x 16B = 16 rows x 32 cols
    const int srow = lane >> 2;
    const int scol = (lane & 3) << 3;
    const unsigned short* gA0 = A + (size_t)(m0 + wave * 16 + srow) * K + scol;
    const unsigned short* gA1 = gA0 + (size_t)64 * K;
    const unsigned short* gB0 = W + (size_t)(n0 + wave * 16 + srow) * K + scol;
    const unsigned short* gB1 = gB0 + (size_t)64 * K;
    unsigned short* lA0 = &sA[wave * 512];
    unsigned short* lA1 = &sA[(wave + 4) * 512];
    unsigned short* lB0 = &sB[wave * 512];
    unsigned short* lB1 = &sB[(wave + 4) * 512];

    f32x4 acc[4][4];
#pragma unroll
    for (int i = 0; i < 4; i++)
#pragma unroll
        for (int j = 0; j < 4; j++) acc[i][j] = (f32x4){0.f, 0.f, 0.f, 0.f};

    // A-fragment: lane holds A[m=lane&15][k=(lane>>4)*8+j]
    const int fl = lane & 15;
    const int fk = (lane >> 4) << 3;
    const unsigned short* aP0 = &sA[(wm * 64 + fl) * 32 + fk];
    const unsigned short* bP0 = &sB[(wn * 64 + fl) * 32 + fk];

    for (int k0 = 0; k0 < K; k0 += 32) {
        __syncthreads();
        GLD_LDS16(gA0 + k0, lA0);
        GLD_LDS16(gA1 + k0, lA1);
        GLD_LDS16(gB0 + k0, lB0);
        GLD_LDS16(gB1 + k0, lB1);
        __syncthreads();

        bf16x8 af[4], bfr[4];
#pragma unroll
        for (int i = 0; i < 4; i++) af[i]  = *(const bf16x8*)(aP0 + i * 512);
#pragma unroll
        for (int j = 0; j < 4; j++) bfr[j] = *(const bf16x8*)(bP0 + j * 512);
#pragma unroll
        for (int i = 0; i < 4; i++)
#pragma unroll
            for (int j = 0; j < 4; j++)
                acc[i][j] = __builtin_amdgcn_mfma_f32_16x16x32_bf16(af[i], bfr[j], acc[i][j], 0, 0, 0);
    }

    // C/D layout: col = lane&15, row = (lane>>4)*4 + r  [m89/m91-verified]
    const int r0 = (lane >> 4) << 2;
#pragma unroll
    for (int j = 0; j < 4; j++) {
        const int col = n0 + wn * 64 + j * 16 + fl;
        const float bj = bias[col];
#pragma unroll
        for (int i = 0; i < 4; i++) {
            const int row = m0 + wm * 64 + i * 16 + r0;
#pragma unroll
            for (int r = 0; r < 4; r++) {
                const float val = acc[i][j][r] + bj;
                if constexpr (OUTF32)
                    ((float*)C)[(size_t)(row + r) * 4096 + col] = val;
                else
                    ((unsigned short*)C)[(size_t)(row + r) * 4096 + col] = f2bf(val);
            }
        }
    }
}

// MFMA per-token attention over the HEAD axis.
// Wave w of block handles token = blockIdx.x*4 + w (fully wave-private; no barriers).
// S = Q K^T (64x64x64), softmax rows over e, O = P V^T, O -> merged layout.
__global__ void __launch_bounds__(256) attn_mfma(
    const unsigned short* __restrict__ q, const unsigned short* __restrict__ k,
    const unsigned short* __restrict__ v, unsigned short* __restrict__ merged)
{
    // per-wave P buffer: 64 rows x 72 shorts (pad 8 -> 2-way banks, 16B-aligned)
    __shared__ __align__(16) unsigned short sP[4][64 * 72];  // 36.9 KB

    const int tid  = threadIdx.x;
    const int wave = tid >> 6;
    const int lane = tid & 63;
    const int token = blockIdx.x * 4 + wave;
    const int b = token >> 6, s = token & 63;
    const size_t base = (size_t)token * 4096;

    const int fl = lane & 15;   // m/n index within a 16-tile
    const int qg = lane >> 4;   // quad group: k-chunk qg*8, acc rows qg*4..+3

    // ---- S = Q K^T : A-frags from q rows, B-frags from k rows, direct global
    f32x4 S[4][4];
#pragma unroll
    for (int i = 0; i < 4; i++)
#pragma unroll
        for (int j = 0; j < 4; j++) S[i][j] = (f32x4){0.f, 0.f, 0.f, 0.f};

#pragma unroll
    for (int ks = 0; ks < 2; ks++) {
        bf16x8 aq[4], bk[4];
#pragma unroll
        for (int t = 0; t < 4; t++) {
            aq[t] = *(const bf16x8*)(q + base + (size_t)(t * 16 + fl) * 64 + ks * 32 + qg * 8);
            bk[t] = *(const bf16x8*)(k + base + (size_t)(t * 16 + fl) * 64 + ks * 32 + qg * 8);
        }
#pragma unroll
        for (int i = 0; i < 4; i++)
#pragma unroll
            for (int j = 0; j < 4; j++)
                S[i][j] = __builtin_amdgcn_mfma_f32_16x16x32_bf16(aq[i], bk[j], S[i][j], 0, 0, 0);
    }

    // ---- softmax over e (cols). Row of S[i][j][r] = i*16 + qg*4 + r; col = j*16+fl.
    float mrow[4][4];
#pragma unroll
    for (int i = 0; i < 4; i++)
#pragma unroll
        for (int r = 0; r < 4; r++) {
            float m = S[i][0][r];
            m = fmaxf(m, S[i][1][r]); m = fmaxf(m, S[i][2][r]); m = fmaxf(m, S[i][3][r]);
            mrow[i][r] = m;
        }
#pragma unroll
    for (int off = 1; off <= 8; off <<= 1)
#pragma unroll
        for (int i = 0; i < 4; i++)
#pragma unroll
            for (int r = 0; r < 4; r++)
                mrow[i][r] = fmaxf(mrow[i][r], __shfl_xor(mrow[i][r], off));

    float lrow[4][4];
#pragma unroll
    for (int i = 0; i < 4; i++)
#pragma unroll
        for (int r = 0; r < 4; r++) lrow[i][r] = 0.f;
#pragma unroll
    for (int i = 0; i < 4; i++)
#pragma unroll
        for (int j = 0; j < 4; j++)
#pragma unroll
            for (int r = 0; r < 4; r++) {
                const float p = __expf((S[i][j][r] - mrow[i][r]) * 0.125f);
                S[i][j][r] = p;
                lrow[i][r] += p;
            }
#pragma unroll
    for (int off = 1; off <= 8; off <<= 1)
#pragma unroll
        for (int i = 0; i < 4; i++)
#pragma unroll
            for (int r = 0; r < 4; r++)
                lrow[i][r] += __shfl_xor(lrow[i][r], off);

    // ---- normalized P -> wave-private LDS (bf16), C-layout scatter
    unsigned short* myP = &sP[wave][0];
#pragma unroll
    for (int i = 0; i < 4; i++)
#pragma unroll
        for (int r = 0; r < 4; r++) {
            const float inv = 1.f / lrow[i][r];
            const int row = i * 16 + qg * 4 + r;
#pragma unroll
            for (int j = 0; j < 4; j++)
                myP[row * 72 + j * 16 + fl] = f2bf(S[i][j][r] * inv);
        }

    // ---- O = P V^T : A-frags of P from LDS, B-frags of V from global
    f32x4 O[4][4];
#pragma unroll
    for (int i = 0; i < 4; i++)
#pragma unroll
        for (int j = 0; j < 4; j++) O[i][j] = (f32x4){0.f, 0.f, 0.f, 0.f};

#pragma unroll
    for (int ks = 0; ks < 2; ks++) {
        bf16x8 ap[4], bv[4];
#pragma unroll
        for (int t = 0; t < 4; t++) {
            ap[t] = *(const bf16x8*)(myP + (t * 16 + fl) * 72 + ks * 32 + qg * 8);
            bv[t] = *(const bf16x8*)(v + base + (size_t)(t * 16 + fl) * 64 + ks * 32 + qg * 8);
        }
#pragma unroll
        for (int i = 0; i < 4; i++)
#pragma unroll
            for (int j = 0; j < 4; j++)
                O[i][j] = __builtin_amdgcn_mfma_f32_16x16x32_bf16(ap[i], bv[j], O[i][j], 0, 0, 0);
    }

    // ---- merged[(b*64 + row)][(s*64 + col)], row = i*16+qg*4+r, col = j*16+fl
#pragma unroll
    for (int i = 0; i < 4; i++)
#pragma unroll
        for (int r = 0; r < 4; r++) {
            const size_t rowbase = (size_t)(b * 64 + i * 16 + qg * 4 + r) * 4096 + s * 64;
#pragma unroll
            for (int j = 0; j < 4; j++)
                merged[rowbase + j * 16 + fl] = f2bf(O[i][j][r]);
        }
}

extern "C" void kernel_launch(void* const* d_in, const int* in_sizes, int n_in,
                              void* d_out, int out_size, void* d_ws, size_t ws_size,
                              hipStream_t stream)
{
    // inputs are FP32 per the reference
    const float* x  = (const float*)d_in[0];
    const float* Wq = (const float*)d_in[1];
    const float* bq = (const float*)d_in[2];
    const float* Wk = (const float*)d_in[3];
    const float* bk = (const float*)d_in[4];
    const float* Wv = (const float*)d_in[5];
    const float* bv = (const float*)d_in[6];
    const float* Wp = (const float*)d_in[7];
    const float* bp = (const float*)d_in[8];
    float* out = (float*)d_out;

    const size_t MAT = (size_t)4096 * 4096;  // elements per bf16 slot (32 MB)
    unsigned short* sw = (unsigned short*)d_ws;
    unsigned short* xb     = sw + 0 * MAT;   // slot0: xb, later merged
    unsigned short* Wqb    = sw + 1 * MAT;   // slot1: Wqb, later Wpb
    unsigned short* Wkb    = sw + 2 * MAT;
    unsigned short* Wvb    = sw + 3 * MAT;
    unsigned short* q      = sw + 4 * MAT;
    unsigned short* k      = sw + 5 * MAT;
    unsigned short* v      = sw + 6 * MAT;   // total 7 slots = 235 MB
    unsigned short* merged = xb;             // x dead after QKV GEMM
    unsigned short* Wpb    = Wqb;            // Wq dead after QKV GEMM

    // 1. convert x, Wq, Wk, Wv to bf16
    cvt_f32_bf16<<<dim3(2048, 1, 4), 256, 0, stream>>>(x, xb, Wq, Wqb, Wk, Wkb, Wv, Wvb);
    // 2. QKV projections (fused)
    gemm_bt<false><<<dim3(32, 32, 3), 256, 0, stream>>>(
        xb, Wqb, bq, q, Wkb, bk, k, Wvb, bv, v);
    // 3. convert Wp into slot1 (Wq dead now)
    cvt_f32_bf16<<<dim3(2048, 1, 1), 256, 0, stream>>>(Wp, Wpb, Wp, Wpb, Wp, Wpb, Wp, Wpb);
    // 4. MFMA per-token head-axis attention -> merged (slot0)
    attn_mfma<<<dim3(1024), 256, 0, stream>>>(q, k, v, merged);
    // 5. output projection -> fp32 d_out
    gemm_bt<true><<<dim3(32, 32, 1), 256, 0, stream>>>(
        merged, Wpb, bp, out, Wpb, bp, out, Wpb, bp, out);
}